// Round 10
// baseline (142.372 us; speedup 1.0000x reference)
//
#include <hip/hip_runtime.h>

#define H 224
#define W 224
#define HW (224 * 224)
#define CIN 3
#define OCH 64

#define TS 32             // output tile: 32x32 px per block (best measured: R3 config)
#define MN 36             // modulated tile: 36x36 (2-halo for 5x5 conv)
#define MSTH 40           // s_mod row stride (halfwords, mult of 4)
#define RN 42             // raw tile: 42x42 (further 3-halo for 7x7 gaussian)
#define RST 44            // s_raw row stride (floats, mult of 4)

typedef __attribute__((ext_vector_type(8))) short short8;
typedef __attribute__((ext_vector_type(4))) float f32x4;

// round-to-nearest-even f32->bf16, packed pair (lo in low 16, hi in high 16)
__device__ __forceinline__ unsigned f2bf_pk(float lo, float hi) {
    unsigned a = __float_as_uint(lo), b = __float_as_uint(hi);
    a = (a + 0x7FFFu + ((a >> 16) & 1u)) >> 16;
    b = (b + 0x7FFFu + ((b >> 16) & 1u)) & 0xFFFF0000u;
    return a | b;
}

// ---- single fused kernel: stage raw+weights -> build A-fragments + modulate
// -> sectioned MFMA conv with non-temporal stores. No prepass dispatch. ----
// SECTIONED K-layout (4 sections of 32):
//   S<3 : channel S, k = ky*8 + kx (ky=0..3 <-> lane q, kx=0..4 <-> j; j>=5 zero)
//   S=3 : ky=4 row of channel q (q=0..2; q=3 all zero), kx <-> j
// Fragment (mt,S): lane (q,li) holds A[oc=mt*16+li][k=q*8+j], j=0..7.
__global__ __launch_bounds__(256, 2) void fused(
    const float* __restrict__ in, const int* __restrict__ foa,
    const float* __restrict__ w, float* __restrict__ out)
{
    __shared__ float  s_raw[CIN][RN][RST];    // 22,176 B
    __shared__ ushort s_mod[CIN][MN][MSTH];   //  8,640 B
    __shared__ float  s_w[OCH * CIN * 25];    // 19,200 B   (total 50,016 B)

    int tid = threadIdx.x;
    int lane = tid & 63;
    int tx0 = blockIdx.x * TS, ty0 = blockIdx.y * TS, b = blockIdx.z;

    // ---- phase 1: stage raw tile + raw weights into LDS ----
    const float* src = in + (size_t)b * CIN * HW;
    for (int i = tid; i < CIN * RN * RN; i += 256) {
        int ch = i / (RN * RN);
        int rem = i - ch * (RN * RN);
        int rr = rem / RN;
        int cc = rem - rr * RN;
        int gr = ty0 - 5 + rr, gc = tx0 - 5 + cc;
        float v = 0.f;
        if ((unsigned)gr < H && (unsigned)gc < W) v = src[ch * HW + gr * W + gc];
        s_raw[ch][rr][cc] = v;
    }
    // weights: 4800 floats = 1200 float4, coalesced
    for (int i = tid; i < 1200; i += 256)
        *(f32x4*)&s_w[i * 4] = *(const f32x4*)&w[i * 4];
    __syncthreads();

    // ---- build per-lane weight A-fragments from LDS (replaces make_wA) ----
    int wv = tid >> 6;
    int q = lane >> 4, li = lane & 15;
    short8 aw[4][4];
#pragma unroll
    for (int mt = 0; mt < 4; ++mt) {
        int oc = mt * 16 + li;
#pragma unroll
        for (int S = 0; S < 4; ++S) {
            float v[8];
#pragma unroll
            for (int j = 0; j < 8; ++j) {
                float x = 0.f;
                if (j < 5) {
                    if (S < 3)      x = s_w[oc * 75 + S * 25 + q * 5 + j];
                    else if (q < 3) x = s_w[oc * 75 + q * 25 + 20 + j];
                }
                v[j] = x;
            }
            union { unsigned u[4]; short8 s8; } cv;
            cv.u[0] = f2bf_pk(v[0], v[1]);
            cv.u[1] = f2bf_pk(v[2], v[3]);
            cv.u[2] = f2bf_pk(v[4], v[5]);
            cv.u[3] = f2bf_pk(v[6], v[7]);
            aw[mt][S] = cv.s8;
        }
    }

    // ---- phase 2: modulate 36x36x3 into s_mod (bf16). unit = ch-row-quad ----
    float fr = (float)foa[2 * b + 0], fc = (float)foa[2 * b + 1];
    for (int u = tid; u < CIN * MN * 9; u += 256) {       // 972 units
        int ch = u / (MN * 9);
        int rem = u - ch * (MN * 9);
        int rm = rem / 9;
        int qc = rem - rm * 9;
        int cm0 = qc * 4;
        int gr = ty0 - 2 + rm;

        float pw[4][7], inv[4];
#pragma unroll
        for (int o = 0; o < 4; ++o) {
            int gc = tx0 - 2 + cm0 + o;
            float dr = (float)gr - fr, dc = (float)gc - fc;
            float dist = sqrtf(dr * dr + dc * dc) * 3.1567268e-3f; // 1/sqrt(2*224^2)
            float sigma = 0.01f + 0.99f * dist;
            float ae = -0.5f / (sigma * sigma);
            float e1 = __expf(ae);
            float e2 = e1 * e1, e4 = e2 * e2, e9 = e4 * e4 * e1;
            pw[o][0] = e9; pw[o][1] = e4; pw[o][2] = e1; pw[o][3] = 1.f;
            pw[o][4] = e1; pw[o][5] = e4; pw[o][6] = e9;
            float S = 1.f + 2.f * (e1 + e4 + e9);
            inv[o] = 1.f / (S * S);
        }
        float acc[4] = {0.f, 0.f, 0.f, 0.f};
#pragma unroll
        for (int ki = 0; ki < 7; ++ki) {
            const float* rp = &s_raw[ch][rm + ki][cm0];   // 16B-aligned
            float rv[10];
            *(f32x4*)&rv[0] = *(const f32x4*)rp;
            *(f32x4*)&rv[4] = *(const f32x4*)(rp + 4);
            *(float2*)&rv[8] = *(const float2*)(rp + 8);
#pragma unroll
            for (int o = 0; o < 4; ++o) {
                float rs = 0.f;
#pragma unroll
                for (int kj = 0; kj < 7; ++kj) rs += pw[o][kj] * rv[o + kj];
                acc[o] += pw[o][ki] * rs;
            }
        }
        float res[4];
#pragma unroll
        for (int o = 0; o < 4; ++o) {
            int gc = tx0 - 2 + cm0 + o;
            bool ok = ((unsigned)gr < H) && ((unsigned)gc < W);
            res[o] = ok ? acc[o] * inv[o] : 0.f;          // zero-pad outside
        }
        uint2 st;
        st.x = f2bf_pk(res[0], res[1]);
        st.y = f2bf_pk(res[2], res[3]);
        *(uint2*)&s_mod[ch][rm][cm0] = st;                // 8B-aligned
    }
    __syncthreads();

    // ---- phase 3: sectioned MFMA conv from LDS, non-temporal stores ----
#pragma unroll
    for (int r8 = 0; r8 < 8; ++r8) {
        int ro = wv * 8 + r8;
#pragma unroll
        for (int s = 0; s < 2; ++s) {
            int co = s * 16 + li;
            int cd = co >> 1;                 // dword offset of even-col base
            unsigned sel = (unsigned)(co & 1) * 16u;

            short8 bf[4];
#pragma unroll
            for (int S = 0; S < 4; ++S) {
                int ch = (S < 3) ? S : (q < 3 ? q : 2);
                int rm = (S < 3) ? (ro + q) : (ro + 4);
                const unsigned* p = (const unsigned*)&s_mod[ch][rm][0] + cd;
                unsigned u0 = p[0], u1 = p[1], u2 = p[2];
                // 5-tap window cols co..co+4; j>=5 slots multiply A=0 (finite data)
                union { unsigned u[4]; short8 s8; } cv;
                cv.u[0] = __builtin_amdgcn_alignbit(u1, u0, sel);
                cv.u[1] = __builtin_amdgcn_alignbit(u2, u1, sel);
                cv.u[2] = u2 >> sel;
                cv.u[3] = 0;
                bf[S] = cv.s8;
            }

            f32x4 acc[4];
#pragma unroll
            for (int mt = 0; mt < 4; ++mt) acc[mt] = (f32x4){0.f, 0.f, 0.f, 0.f};
#pragma unroll
            for (int S = 0; S < 4; ++S)
#pragma unroll
                for (int mt = 0; mt < 4; ++mt)
                    acc[mt] = __builtin_amdgcn_mfma_f32_16x16x32_bf16(
                        aw[mt][S], bf[S], acc[mt], 0, 0, 0);

            int px = tx0 + co, py = ty0 + ro;
#pragma unroll
            for (int mt = 0; mt < 4; ++mt) {
#pragma unroll
                for (int r = 0; r < 4; ++r) {
                    int oc = mt * 16 + q * 4 + r;
                    // out is write-once, never re-read: bypass L2 with nt store
                    __builtin_nontemporal_store(
                        acc[mt][r],
                        &out[(size_t)(b * OCH + oc) * HW + (size_t)py * W + px]);
                }
            }
        }
    }
}

extern "C" void kernel_launch(void* const* d_in, const int* in_sizes, int n_in,
                              void* d_out, int out_size, void* d_ws, size_t ws_size,
                              hipStream_t stream) {
    const float* input  = (const float*)d_in[0];   // (8,3,224,224) fp32
    const int*   foa    = (const int*)d_in[1];     // (8,2) int32
    const float* weight = (const float*)d_in[2];   // (64,3,5,5) fp32
    float* outp = (float*)d_out;                   // (8,64,224,224) fp32

    dim3 grid(W / TS, H / TS, 8);                  // 7 x 7 x 8 = 392 blocks
    fused<<<grid, 256, 0, stream>>>(input, foa, weight, outp);
}

// Round 11
// 126.445 us; speedup vs baseline: 1.1260x; 1.1260x over previous
//
#include <hip/hip_runtime.h>

#define H 224
#define W 224
#define HW (224 * 224)
#define CIN 3
#define OCH 64

#define TS 32             // output tile: 32x32 px per block
#define MN 36             // modulated tile: 36x36 (2-halo for 5x5 conv)
#define MSTH 40           // s_mod row stride (halfwords, mult of 4)
#define RN 42             // raw tile: 42x42 (further 3-halo for 7x7 gaussian)
#define RST 44            // s_raw row stride (floats, mult of 4)

typedef __attribute__((ext_vector_type(8))) short short8;
typedef __attribute__((ext_vector_type(4))) float f32x4;

// round-to-nearest-even f32->bf16, packed pair (lo in low 16, hi in high 16)
__device__ __forceinline__ unsigned f2bf_pk(float lo, float hi) {
    unsigned a = __float_as_uint(lo), b = __float_as_uint(hi);
    a = (a + 0x7FFFu + ((a >> 16) & 1u)) >> 16;
    b = (b + 0x7FFFu + ((b >> 16) & 1u)) & 0xFFFF0000u;
    return a | b;
}

// ---- weight prepass: (64,3,5,5) -> bf16 A-fragments, SECTIONED K-layout ----
// 4 K-sections of 32:
//   S<3 : channel S, k = ky*8 + kx (ky=0..3 <-> lane q, kx=0..4 <-> j; j>=5 zero)
//   S=3 : ky=4 row of channel q (q=0..2; q=3 all zero), kx <-> j
// Fragment (mt,S): lane (q,li) holds A[oc=mt*16+li][k=q*8+j], j=0..7.
__global__ void make_wA(const float* __restrict__ w, uint4* __restrict__ wA) {
    int t = threadIdx.x;          // 1024 threads, exact
    int lane = t & 63;
    int fi = t >> 6;              // 0..15 = mt*4 + S
    int mt = fi >> 2, S = fi & 3;
    int q = lane >> 4;
    int oc = mt * 16 + (lane & 15);
    float v[8];
#pragma unroll
    for (int j = 0; j < 8; ++j) {
        float x = 0.f;
        if (j < 5) {
            if (S < 3) x = w[oc * 75 + S * 25 + q * 5 + j];
            else if (q < 3) x = w[oc * 75 + q * 25 + 20 + j];
        }
        v[j] = x;
    }
    uint4 r;
    r.x = f2bf_pk(v[0], v[1]);
    r.y = f2bf_pk(v[2], v[3]);
    r.z = f2bf_pk(v[4], v[5]);
    r.w = f2bf_pk(v[6], v[7]);
    wA[fi * 64 + lane] = r;
}

// ---- fused: stage raw -> modulate (LDS, bf16) -> sectioned MFMA conv ----
// Best-measured config (R3/R7): 32x32 tile, 392 blocks, lb(256,2),
// two barriers, plain coalesced stores, make_wA as separate tiny dispatch.
__global__ __launch_bounds__(256, 2) void fused(
    const uint4* __restrict__ wA, const float* __restrict__ in,
    const int* __restrict__ foa, float* __restrict__ out)
{
    __shared__ float  s_raw[CIN][RN][RST];    // 22,176 B
    __shared__ ushort s_mod[CIN][MN][MSTH];   //  8,640 B

    int tid = threadIdx.x;
    int lane = tid & 63;
    int tx0 = blockIdx.x * TS, ty0 = blockIdx.y * TS, b = blockIdx.z;

    // prefetch weight fragments (16 KB table, L2-hot); hidden under staging
    short8 aw[4][4];
#pragma unroll
    for (int mt = 0; mt < 4; ++mt)
#pragma unroll
        for (int S = 0; S < 4; ++S) {
            union { uint4 u4; short8 s8; } cv;
            cv.u4 = wA[(mt * 4 + S) * 64 + lane];
            aw[mt][S] = cv.s8;
        }

    // ---- phase 1: stage raw tile (rows ty0-5..ty0+36, cols tx0-5..tx0+36) ----
    const float* src = in + (size_t)b * CIN * HW;
    for (int i = tid; i < CIN * RN * RN; i += 256) {
        int ch = i / (RN * RN);
        int rem = i - ch * (RN * RN);
        int rr = rem / RN;
        int cc = rem - rr * RN;
        int gr = ty0 - 5 + rr, gc = tx0 - 5 + cc;
        float v = 0.f;
        if ((unsigned)gr < H && (unsigned)gc < W) v = src[ch * HW + gr * W + gc];
        s_raw[ch][rr][cc] = v;
    }
    __syncthreads();

    // ---- phase 2: modulate 36x36x3 into s_mod (bf16). unit = ch-row-quad ----
    float fr = (float)foa[2 * b + 0], fc = (float)foa[2 * b + 1];
    for (int u = tid; u < CIN * MN * 9; u += 256) {       // 972 units
        int ch = u / (MN * 9);
        int rem = u - ch * (MN * 9);
        int rm = rem / 9;
        int qc = rem - rm * 9;
        int cm0 = qc * 4;
        int gr = ty0 - 2 + rm;

        float pw[4][7], inv[4];
#pragma unroll
        for (int o = 0; o < 4; ++o) {
            int gc = tx0 - 2 + cm0 + o;
            float dr = (float)gr - fr, dc = (float)gc - fc;
            float dist = sqrtf(dr * dr + dc * dc) * 3.1567268e-3f; // 1/sqrt(2*224^2)
            float sigma = 0.01f + 0.99f * dist;
            float ae = -0.5f / (sigma * sigma);
            float e1 = __expf(ae);
            float e2 = e1 * e1, e4 = e2 * e2, e9 = e4 * e4 * e1;
            pw[o][0] = e9; pw[o][1] = e4; pw[o][2] = e1; pw[o][3] = 1.f;
            pw[o][4] = e1; pw[o][5] = e4; pw[o][6] = e9;
            float S = 1.f + 2.f * (e1 + e4 + e9);
            inv[o] = 1.f / (S * S);
        }
        float acc[4] = {0.f, 0.f, 0.f, 0.f};
#pragma unroll
        for (int ki = 0; ki < 7; ++ki) {
            const float* rp = &s_raw[ch][rm + ki][cm0];   // 16B-aligned
            float rv[10];
            *(f32x4*)&rv[0] = *(const f32x4*)rp;
            *(f32x4*)&rv[4] = *(const f32x4*)(rp + 4);
            *(float2*)&rv[8] = *(const float2*)(rp + 8);
#pragma unroll
            for (int o = 0; o < 4; ++o) {
                float rs = 0.f;
#pragma unroll
                for (int kj = 0; kj < 7; ++kj) rs += pw[o][kj] * rv[o + kj];
                acc[o] += pw[o][ki] * rs;
            }
        }
        float res[4];
#pragma unroll
        for (int o = 0; o < 4; ++o) {
            int gc = tx0 - 2 + cm0 + o;
            bool ok = ((unsigned)gr < H) && ((unsigned)gc < W);
            res[o] = ok ? acc[o] * inv[o] : 0.f;          // zero-pad outside
        }
        uint2 st;
        st.x = f2bf_pk(res[0], res[1]);
        st.y = f2bf_pk(res[2], res[3]);
        *(uint2*)&s_mod[ch][rm][cm0] = st;                // 8B-aligned
    }
    __syncthreads();

    // ---- phase 3: sectioned MFMA conv from LDS ----
    int wv = tid >> 6;
    int q = lane >> 4, li = lane & 15;

#pragma unroll
    for (int r8 = 0; r8 < 8; ++r8) {
        int ro = wv * 8 + r8;
#pragma unroll
        for (int s = 0; s < 2; ++s) {
            int co = s * 16 + li;
            int cd = co >> 1;                 // dword offset of even-col base
            unsigned sel = (unsigned)(co & 1) * 16u;

            short8 bf[4];
#pragma unroll
            for (int S = 0; S < 4; ++S) {
                int ch = (S < 3) ? S : (q < 3 ? q : 2);
                int rm = (S < 3) ? (ro + q) : (ro + 4);
                const unsigned* p = (const unsigned*)&s_mod[ch][rm][0] + cd;
                unsigned u0 = p[0], u1 = p[1], u2 = p[2];
                // 5-tap window cols co..co+4; j>=5 slots multiply A=0 (finite data)
                union { unsigned u[4]; short8 s8; } cv;
                cv.u[0] = __builtin_amdgcn_alignbit(u1, u0, sel);
                cv.u[1] = __builtin_amdgcn_alignbit(u2, u1, sel);
                cv.u[2] = u2 >> sel;
                cv.u[3] = 0;
                bf[S] = cv.s8;
            }

            f32x4 acc[4];
#pragma unroll
            for (int mt = 0; mt < 4; ++mt) acc[mt] = (f32x4){0.f, 0.f, 0.f, 0.f};
#pragma unroll
            for (int S = 0; S < 4; ++S)
#pragma unroll
                for (int mt = 0; mt < 4; ++mt)
                    acc[mt] = __builtin_amdgcn_mfma_f32_16x16x32_bf16(
                        aw[mt][S], bf[S], acc[mt], 0, 0, 0);

            int px = tx0 + co, py = ty0 + ro;
#pragma unroll
            for (int mt = 0; mt < 4; ++mt) {
#pragma unroll
                for (int r = 0; r < 4; ++r) {
                    int oc = mt * 16 + q * 4 + r;
                    out[(size_t)(b * OCH + oc) * HW + (size_t)py * W + px] = acc[mt][r];
                }
            }
        }
    }
}

extern "C" void kernel_launch(void* const* d_in, const int* in_sizes, int n_in,
                              void* d_out, int out_size, void* d_ws, size_t ws_size,
                              hipStream_t stream) {
    const float* input  = (const float*)d_in[0];   // (8,3,224,224) fp32
    const int*   foa    = (const int*)d_in[1];     // (8,2) int32
    const float* weight = (const float*)d_in[2];   // (64,3,5,5) fp32
    float* outp = (float*)d_out;                   // (8,64,224,224) fp32

    uint4* wA = (uint4*)d_ws;                      // 16 KB

    make_wA<<<1, 1024, 0, stream>>>(weight, wA);

    dim3 grid(W / TS, H / TS, 8);                  // 7 x 7 x 8 = 392 blocks
    fused<<<grid, 256, 0, stream>>>(wA, input, foa, outp);
}